// Round 11
// baseline (113.194 us; speedup 1.0000x reference)
//
#include <hip/hip_runtime.h>
#include <hip/hip_bf16.h>

#define B_   2
#define S_   2048
#define D_   768
#define H_   12
#define DK_  64
#define R_   (B_*S_)   // 4096 rows total
#define LOG2E_OVER8 0.18033688011112042f

typedef __attribute__((ext_vector_type(8))) short short8;
typedef __attribute__((ext_vector_type(4))) float f32x4;

__device__ __forceinline__ short f2b(float f) {
  union { float f; unsigned u; } x; x.f = f;
  unsigned r = x.u + 0x7fffu + ((x.u >> 16) & 1u);
  return (short)(r >> 16);
}

__device__ __forceinline__ unsigned cvt_pk_bf16(float lo, float hi) {
  unsigned r;
  asm("v_cvt_pk_bf16_f32 %0, %1, %2" : "=v"(r) : "v"(lo), "v"(hi));
  return r;
}

__device__ __forceinline__ void gl_lds16(const short* g, short* l) {
  __builtin_amdgcn_global_load_lds(
      (const __attribute__((address_space(1))) void*)g,
      (__attribute__((address_space(3))) void*)l, 16, 0, 0);
}

// ---------------- fp32 -> bf16 conversion (x + 4 weights) ----------------
__global__ void cvt_kernel(const float* __restrict__ x,
                           const float* __restrict__ wq, const float* __restrict__ wk,
                           const float* __restrict__ wv, const float* __restrict__ wo,
                           short* __restrict__ xb, short* __restrict__ wb) {
  const int XQ = R_ * D_ / 4;
  const int WQ = D_ * D_ / 4;
  int idx = blockIdx.x * blockDim.x + threadIdx.x;
  const float* src; short* dst; int off;
  if (idx < XQ) { src = x; dst = xb; off = idx; }
  else {
    int wi = idx - XQ; int w = wi / WQ; off = wi - w * WQ;
    if      (w == 0) { src = wq; dst = wb; }
    else if (w == 1) { src = wk; dst = wb + D_*D_; }
    else if (w == 2) { src = wv; dst = wb + 2*D_*D_; }
    else             { src = wo; dst = wb + 3*D_*D_; }
  }
  float4 v = ((const float4*)src)[off];
  short4 o;
  o.x = f2b(v.x); o.y = f2b(v.y); o.z = f2b(v.z); o.w = f2b(v.w);
  ((short4*)dst)[off] = o;
}

// ---------------- QKV projection (128x128, dbuf, 1 barrier/K-step) ----------------
__launch_bounds__(256)
__global__ void qkv_gemm_kernel(const short* __restrict__ xb, const short* __restrict__ wb,
                                const float* __restrict__ bq, const float* __restrict__ bk,
                                const float* __restrict__ bv,
                                short* __restrict__ Qw, short* __restrict__ Kw,
                                short* __restrict__ VTw) {
  __shared__ short As[2][128 * 32];
  __shared__ short Bs[2][128 * 32];
  const int which = blockIdx.z;
  const short* W = wb + which * (D_ * D_);
  const float* bias = (which == 0) ? bq : (which == 1) ? bk : bv;
  const int n0 = blockIdx.x * 128, m0 = blockIdx.y * 128;
  const int t = threadIdx.x, l = t & 63, w = t >> 6;
  const int wr = w >> 1, wc = w & 1;

  f32x4 acc[4][4] = {};
  const int srow = t >> 2, sseg = (t & 3) * 8;

#define GSTAGE(buf, k0) do { \
    gl_lds16(xb + (m0 + srow) * D_ + (k0) + sseg,      &As[buf][t * 8]); \
    gl_lds16(xb + (m0 + 64 + srow) * D_ + (k0) + sseg, &As[buf][(t + 256) * 8]); \
    gl_lds16(W  + (n0 + srow) * D_ + (k0) + sseg,      &Bs[buf][t * 8]); \
    gl_lds16(W  + (n0 + 64 + srow) * D_ + (k0) + sseg, &Bs[buf][(t + 256) * 8]); \
  } while (0)

  GSTAGE(0, 0);
  __syncthreads();
  int cur = 0;
  for (int k0 = 0; k0 < D_; k0 += 32) {
    if (k0 + 32 < D_) GSTAGE(cur ^ 1, k0 + 32);
    short8 a[4], b[4];
#pragma unroll
    for (int i = 0; i < 4; i++)
      a[i] = *(const short8*)&As[cur][(wr * 64 + i * 16 + (l & 15)) * 32 + (l >> 4) * 8];
#pragma unroll
    for (int i = 0; i < 4; i++)
      b[i] = *(const short8*)&Bs[cur][(wc * 64 + i * 16 + (l & 15)) * 32 + (l >> 4) * 8];
#pragma unroll
    for (int i = 0; i < 4; i++)
#pragma unroll
      for (int j = 0; j < 4; j++)
        acc[i][j] = __builtin_amdgcn_mfma_f32_16x16x32_bf16(a[i], b[j], acc[i][j], 0, 0, 0);
    __syncthreads();
    cur ^= 1;
  }
#undef GSTAGE

#pragma unroll
  for (int i = 0; i < 4; i++) {
#pragma unroll
    for (int j2 = 0; j2 < 4; j2++) {
      int mm = m0 + wr * 64 + i * 16 + (l >> 4) * 4 + j2;
      int bidx = mm >> 11, s = mm & 2047;
#pragma unroll
      for (int nj = 0; nj < 4; nj++) {
        int e = n0 + wc * 64 + nj * 16 + (l & 15);
        float val = acc[i][nj][j2] + bias[e];
        int h = e >> 6, dk = e & 63;
        int bh = bidx * H_ + h;
        if (which == 0)      Qw[(bh * S_ + s) * DK_ + dk] = f2b(val * LOG2E_OVER8);
        else if (which == 1) Kw[(bh * S_ + s) * DK_ + dk] = f2b(val);
        else                 VTw[(bh * DK_ + dk) * S_ + s] = f2b(val);
      }
    }
  }
}

// ---------------- flash attention v11: QBLK=64/wave, 4 kv-streams ----------------
// 256 threads = 4 waves; wave s owns kv quarter [s*512, (s+1)*512), all 64 q.
// Per-tile dataflow is v10-exact (swapped QK, fixed-scale exp2 softmax,
// in-register P pack, remapped-k PV); mi extended 2->4, K/V LDS reads shared
// across 4 mi -> LDS-per-MFMA halved. 4-way additive merge at the end.
#define KVB  32
#define SQTR 512
__launch_bounds__(256, 2)
__global__ void attn_kernel(const short* __restrict__ Qw, const short* __restrict__ Kw,
                            const short* __restrict__ VTw, short* __restrict__ ctx) {
  __shared__ short Ksh[4][2][KVB * DK_];   // 4 streams x 2 bufs x 4KB = 32KB
  __shared__ short Vsh[4][2][KVB * DK_];   // 32KB (pair-packed rows)
  __shared__ float Lsh[3][64];             // l partials from streams 1..3

  const int t = threadIdx.x, l = t & 63, s = t >> 6;
  // bijective XCD swizzle: 768 blocks -> (xcd, head-in-xcd, q-block)
  const int L = blockIdx.y * 32 + blockIdx.x;
  const int xcd = L & 7, idx = L >> 3;
  const int bh = xcd * 3 + (idx >> 5);
  const int qblk = idx & 31;
  const int q0 = qblk * 64;
  const int bq = bh / H_, h = bh - bq * H_;
  const short* Qh = Qw + bh * S_ * DK_;
  const short* Kh = Kw + (bh * S_ + s * SQTR) * DK_;
  const short* Vh = VTw + bh * DK_ * S_ + s * SQTR;

  // staging: each wave stages its own stream's 8KB tile, 8 chunks/thread.
  // chunk i = l + 64j: K row r = (l>>3) + 8j, col-chunk c = l&7 (src swizzled).
  const int c0 = l & 7, r0 = l >> 3;                 // r0 in [0,8)
  const int koff0 = r0 * DK_ + ((c0 ^ r0) << 3);
  const int vc8 = c0 ^ r0;                           // rp & 7 == r0 for all j
  const int vr0 = 2 * r0 + (vc8 >> 2);
  const int voff0 = vr0 * S_ + ((vc8 & 3) << 3);

#define STAGE(buf, kt) do { \
    _Pragma("unroll") \
    for (int j = 0; j < 4; j++) { \
      gl_lds16(Kh + (kt) * DK_ + koff0 + 512 * j, &Ksh[s][buf][l * 8 + 512 * j]); \
      gl_lds16(Vh + (kt) + voff0 + 16 * S_ * j,   &Vsh[s][buf][l * 8 + 512 * j]); \
    } \
  } while (0)

  // Q fragments in registers (pre-scaled by log2e/8 at projection)
  short8 qf[4][2];
#pragma unroll
  for (int mi = 0; mi < 4; mi++)
#pragma unroll
    for (int ks = 0; ks < 2; ks++)
      qf[mi][ks] = *(const short8*)&Qh[(q0 + 16 * mi + (l & 15)) * DK_ + ks * 32 + (l >> 4) * 8];

  f32x4 acc_o[4][4] = {};
  float l_run[4] = {0.f, 0.f, 0.f, 0.f};

  STAGE(0, 0);
  __syncthreads();
  int cur = 0;

  for (int kt = 0; kt < SQTR; kt += KVB) {
    if (kt + KVB < SQTR) STAGE(cur ^ 1, kt + KVB);

    // ---- QK^T (swapped): lane holds scores for q=16mi+(l&15), k=16ni+4(l>>4)+j ----
    f32x4 acc_s[4][2] = {};
    __builtin_amdgcn_s_setprio(1);
#pragma unroll
    for (int ni = 0; ni < 2; ni++) {
      int r = (l & 15) + 16 * ni;
#pragma unroll
      for (int ks = 0; ks < 2; ks++) {
        int cc = (l >> 4) + 4 * ks;
        short8 kf = *(const short8*)&Ksh[s][cur][r * DK_ + ((cc ^ (r & 7)) << 3)];
#pragma unroll
        for (int mi = 0; mi < 4; mi++)
          acc_s[mi][ni] = __builtin_amdgcn_mfma_f32_16x16x32_bf16(kf, qf[mi][ks], acc_s[mi][ni], 0, 0, 0);
      }
    }
    __builtin_amdgcn_s_setprio(0);

    // ---- fixed-scale softmax: p = exp2(score), per-lane partial sums ----
    union PK { unsigned u[4]; short8 v; } pa[4];
#pragma unroll
    for (int mi = 0; mi < 4; mi++) {
      float sum = 0.f;
#pragma unroll
      for (int ni = 0; ni < 2; ni++)
#pragma unroll
        for (int j = 0; j < 4; j++) {
          float p = __builtin_amdgcn_exp2f(acc_s[mi][ni][j]);
          acc_s[mi][ni][j] = p;
          sum += p;
        }
      l_run[mi] += sum;
      pa[mi].u[0] = cvt_pk_bf16(acc_s[mi][0][0], acc_s[mi][0][1]);
      pa[mi].u[1] = cvt_pk_bf16(acc_s[mi][0][2], acc_s[mi][0][3]);
      pa[mi].u[2] = cvt_pk_bf16(acc_s[mi][1][0], acc_s[mi][1][1]);
      pa[mi].u[3] = cvt_pk_bf16(acc_s[mi][1][2], acc_s[mi][1][3]);
    }

    // ---- PV: B = V rows in remapped k-order (b64x2), shared across 4 mi ----
    __builtin_amdgcn_s_setprio(1);
    {
      const int cc = l >> 4;
      union V8 { short4 h[2]; short8 v; };
#pragma unroll
      for (int nd = 0; nd < 4; nd++) {
        int vr = (l & 15) + 16 * nd, rp = vr >> 1;
        int ph0 = (((vr & 1) << 2) | (cc >> 1)) ^ (rp & 7);
        int ph1 = (((vr & 1) << 2) | (2 + (cc >> 1))) ^ (rp & 7);
        V8 vf;
        vf.h[0] = *(const short4*)&Vsh[s][cur][rp * 64 + ph0 * 8 + (cc & 1) * 4];
        vf.h[1] = *(const short4*)&Vsh[s][cur][rp * 64 + ph1 * 8 + (cc & 1) * 4];
#pragma unroll
        for (int mi = 0; mi < 4; mi++)
          acc_o[mi][nd] = __builtin_amdgcn_mfma_f32_16x16x32_bf16(pa[mi].v, vf.v, acc_o[mi][nd], 0, 0, 0);
      }
    }
    __builtin_amdgcn_s_setprio(0);

    __syncthreads();   // staged tile ready + WAR fence
    cur ^= 1;
  }

  // ---- reduce per-lane l partials across the 4 lane-groups ----
#pragma unroll
  for (int mi = 0; mi < 4; mi++) {
    l_run[mi] += __shfl_xor(l_run[mi], 16);
    l_run[mi] += __shfl_xor(l_run[mi], 32);
  }

  // ---- 4-way additive merge: streams 1..3 publish, stream 0 combines ----
  __syncthreads();                          // K/V LDS dead from here
  float* O12 = (float*)&Ksh[0][0][0];       // 8192 floats: stream1 @0, stream2 @4096
  float* O3  = (float*)&Vsh[0][0][0];       // 4096 floats: stream3
  if (s >= 1) {
    float* dst = (s == 1) ? O12 : (s == 2) ? O12 + 4096 : O3;
#pragma unroll
    for (int mi = 0; mi < 4; mi++)
#pragma unroll
      for (int nd = 0; nd < 4; nd++)
#pragma unroll
        for (int j = 0; j < 4; j++)
          dst[(16 * mi + (l >> 4) * 4 + j) * 64 + (l & 15) + 16 * nd] = acc_o[mi][nd][j];
    if (l < 16) {
#pragma unroll
      for (int mi = 0; mi < 4; mi++) Lsh[s - 1][16 * mi + l] = l_run[mi];
    }
  }
  __syncthreads();
  if (s == 0) {
#pragma unroll
    for (int mi = 0; mi < 4; mi++) {
#pragma unroll
      for (int j = 0; j < 4; j++) {
        int src = ((l >> 4) << 2) + j;       // q-row within 16, also source lane
        int qrow = 16 * mi + src;
        float lsum = __shfl(l_run[mi], src) + Lsh[0][qrow] + Lsh[1][qrow] + Lsh[2][qrow];
        float inv = 1.f / lsum;
#pragma unroll
        for (int nd = 0; nd < 4; nd++) {
          int dcol = (l & 15) + 16 * nd;
          float v = acc_o[mi][nd][j] + O12[qrow * 64 + dcol]
                  + O12[4096 + qrow * 64 + dcol] + O3[qrow * 64 + dcol];
          ctx[(bq * S_ + q0 + qrow) * D_ + h * DK_ + dcol] = f2b(v * inv);
        }
      }
    }
  }
#undef STAGE
}

// ---------------- output projection (128x128, dbuf) ----------------
__launch_bounds__(256)
__global__ void oproj_kernel(const short* __restrict__ ctx, const short* __restrict__ Wo,
                             const float* __restrict__ bo, float* __restrict__ out) {
  __shared__ short As[2][128 * 32];
  __shared__ short Bs[2][128 * 32];
  const int n0 = blockIdx.x * 128, m0 = blockIdx.y * 128;
  const int t = threadIdx.x, l = t & 63, w = t >> 6;
  const int wr = w >> 1, wc = w & 1;

  f32x4 acc[4][4] = {};
  const int srow = t >> 2, sseg = (t & 3) * 8;

#define GSTAGE(buf, k0) do { \
    gl_lds16(ctx + (m0 + srow) * D_ + (k0) + sseg,      &As[buf][t * 8]); \
    gl_lds16(ctx + (m0 + 64 + srow) * D_ + (k0) + sseg, &As[buf][(t + 256) * 8]); \
    gl_lds16(Wo  + (n0 + srow) * D_ + (k0) + sseg,      &Bs[buf][t * 8]); \
    gl_lds16(Wo  + (n0 + 64 + srow) * D_ + (k0) + sseg, &Bs[buf][(t + 256) * 8]); \
  } while (0)

  GSTAGE(0, 0);
  __syncthreads();
  int cur = 0;
  for (int k0 = 0; k0 < D_; k0 += 32) {
    if (k0 + 32 < D_) GSTAGE(cur ^ 1, k0 + 32);
    short8 a[4], b[4];
#pragma unroll
    for (int i = 0; i < 4; i++)
      a[i] = *(const short8*)&As[cur][(wr * 64 + i * 16 + (l & 15)) * 32 + (l >> 4) * 8];
#pragma unroll
    for (int i = 0; i < 4; i++)
      b[i] = *(const short8*)&Bs[cur][(wc * 64 + i * 16 + (l & 15)) * 32 + (l >> 4) * 8];
#pragma unroll
    for (int i = 0; i < 4; i++)
#pragma unroll
      for (int j = 0; j < 4; j++)
        acc[i][j] = __builtin_amdgcn_mfma_f32_16x16x32_bf16(a[i], b[j], acc[i][j], 0, 0, 0);
    __syncthreads();
    cur ^= 1;
  }
#undef GSTAGE

#pragma unroll
  for (int i = 0; i < 4; i++) {
#pragma unroll
    for (int j2 = 0; j2 < 4; j2++) {
      int mm = m0 + wr * 64 + i * 16 + (l >> 4) * 4 + j2;
#pragma unroll
      for (int nj = 0; nj < 4; nj++) {
        int e = n0 + wc * 64 + nj * 16 + (l & 15);
        out[mm * D_ + e] = acc[i][nj][j2] + bo[e];
      }
    }
  }
}

extern "C" void kernel_launch(void* const* d_in, const int* in_sizes, int n_in,
                              void* d_out, int out_size, void* d_ws, size_t ws_size,
                              hipStream_t stream) {
  (void)in_sizes; (void)n_in; (void)out_size; (void)ws_size;
  const float* x  = (const float*)d_in[0];
  const float* wq = (const float*)d_in[1];
  const float* bq = (const float*)d_in[2];
  const float* wk = (const float*)d_in[3];
  const float* bk = (const float*)d_in[4];
  const float* wv = (const float*)d_in[5];
  const float* bv = (const float*)d_in[6];
  const float* wo = (const float*)d_in[7];
  const float* bo = (const float*)d_in[8];
  float* out = (float*)d_out;

  short* xb  = (short*)d_ws;            // R*D bf16
  short* wb  = xb + R_ * D_;            // 4*D*D bf16 (q,k,v,o)
  short* Qw  = wb + 4 * D_ * D_;        // [B,H,S,DK]
  short* Kw  = Qw + R_ * D_;            // [B,H,S,DK]
  short* VTw = Kw + R_ * D_;            // [B,H,DK,S]
  short* ctx = VTw + R_ * D_;           // [B,S,D]

  cvt_kernel<<<5376, 256, 0, stream>>>(x, wq, wk, wv, wo, xb, wb);
  qkv_gemm_kernel<<<dim3(6, 32, 3), 256, 0, stream>>>(xb, wb, bq, bk, bv, Qw, Kw, VTw);
  attn_kernel<<<dim3(32, 24), 256, 0, stream>>>(Qw, Kw, VTw, ctx);
  oproj_kernel<<<dim3(6, 32), 256, 0, stream>>>(ctx, wb + 3 * D_ * D_, bo, out);
}

// Round 12
// 100.986 us; speedup vs baseline: 1.1209x; 1.1209x over previous
//
#include <hip/hip_runtime.h>
#include <hip/hip_bf16.h>

#define B_   2
#define S_   2048
#define D_   768
#define H_   12
#define DK_  64
#define R_   (B_*S_)   // 4096 rows total
#define LOG2E_OVER8 0.18033688011112042f

typedef __attribute__((ext_vector_type(8))) short short8;
typedef __attribute__((ext_vector_type(4))) float f32x4;

__device__ __forceinline__ short f2b(float f) {
  union { float f; unsigned u; } x; x.f = f;
  unsigned r = x.u + 0x7fffu + ((x.u >> 16) & 1u);
  return (short)(r >> 16);
}

__device__ __forceinline__ unsigned cvt_pk_bf16(float lo, float hi) {
  unsigned r;
  asm("v_cvt_pk_bf16_f32 %0, %1, %2" : "=v"(r) : "v"(lo), "v"(hi));
  return r;
}

__device__ __forceinline__ void gl_lds16(const short* g, short* l) {
  __builtin_amdgcn_global_load_lds(
      (const __attribute__((address_space(1))) void*)g,
      (__attribute__((address_space(3))) void*)l, 16, 0, 0);
}

// ---------------- fp32 -> bf16 conversion (x + 4 weights) ----------------
__global__ void cvt_kernel(const float* __restrict__ x,
                           const float* __restrict__ wq, const float* __restrict__ wk,
                           const float* __restrict__ wv, const float* __restrict__ wo,
                           short* __restrict__ xb, short* __restrict__ wb) {
  const int XQ = R_ * D_ / 4;
  const int WQ = D_ * D_ / 4;
  int idx = blockIdx.x * blockDim.x + threadIdx.x;
  const float* src; short* dst; int off;
  if (idx < XQ) { src = x; dst = xb; off = idx; }
  else {
    int wi = idx - XQ; int w = wi / WQ; off = wi - w * WQ;
    if      (w == 0) { src = wq; dst = wb; }
    else if (w == 1) { src = wk; dst = wb + D_*D_; }
    else if (w == 2) { src = wv; dst = wb + 2*D_*D_; }
    else             { src = wo; dst = wb + 3*D_*D_; }
  }
  float4 v = ((const float4*)src)[off];
  short4 o;
  o.x = f2b(v.x); o.y = f2b(v.y); o.z = f2b(v.z); o.w = f2b(v.w);
  ((short4*)dst)[off] = o;
}

// ------- QKV projection: 128x128 tile, 3-buffer ring, counted vmcnt (T3/T4) -------
__launch_bounds__(256)
__global__ void qkv_gemm_kernel(const short* __restrict__ xb, const short* __restrict__ wb,
                                const float* __restrict__ bq, const float* __restrict__ bk,
                                const float* __restrict__ bv,
                                short* __restrict__ Qw, short* __restrict__ Kw,
                                short* __restrict__ VTw) {
  __shared__ short As[3][128 * 32];   // 24KB
  __shared__ short Bs[3][128 * 32];   // 24KB
  const int which = blockIdx.z;
  const short* W = wb + which * (D_ * D_);
  const float* bias = (which == 0) ? bq : (which == 1) ? bk : bv;
  const int n0 = blockIdx.x * 128, m0 = blockIdx.y * 128;
  const int t = threadIdx.x, l = t & 63, w = t >> 6;
  const int wr = w >> 1, wc = w & 1;

  f32x4 acc[4][4] = {};
  const int srow = t >> 2, sseg = (t & 3) * 8;

#define GSTAGE(buf, k0) do { \
    gl_lds16(xb + (m0 + srow) * D_ + (k0) + sseg,      &As[buf][t * 8]); \
    gl_lds16(xb + (m0 + 64 + srow) * D_ + (k0) + sseg, &As[buf][(t + 256) * 8]); \
    gl_lds16(W  + (n0 + srow) * D_ + (k0) + sseg,      &Bs[buf][t * 8]); \
    gl_lds16(W  + (n0 + 64 + srow) * D_ + (k0) + sseg, &Bs[buf][(t + 256) * 8]); \
  } while (0)

  GSTAGE(0, 0);
  GSTAGE(1, 32);
  int step = 0;
#pragma unroll 1
  for (int k0 = 0; k0 < D_; k0 += 32, step++) {
    // wait own oldest stage (4 loads) done; next stage's 4 stay in flight
    if (k0 + 32 < D_) {
      asm volatile("s_waitcnt vmcnt(4)" ::: "memory");
    } else {
      asm volatile("s_waitcnt vmcnt(0)" ::: "memory");
    }
    __builtin_amdgcn_sched_barrier(0);
    __builtin_amdgcn_s_barrier();           // tile[step] complete in LDS, all waves
    if (k0 + 64 < D_) GSTAGE((step + 2) % 3, k0 + 64);   // WAR safe: last read step-1
    const int cb = step % 3;
    short8 a[4], b[4];
#pragma unroll
    for (int i = 0; i < 4; i++)
      a[i] = *(const short8*)&As[cb][(wr * 64 + i * 16 + (l & 15)) * 32 + (l >> 4) * 8];
#pragma unroll
    for (int i = 0; i < 4; i++)
      b[i] = *(const short8*)&Bs[cb][(wc * 64 + i * 16 + (l & 15)) * 32 + (l >> 4) * 8];
#pragma unroll
    for (int i = 0; i < 4; i++)
#pragma unroll
      for (int j = 0; j < 4; j++)
        acc[i][j] = __builtin_amdgcn_mfma_f32_16x16x32_bf16(a[i], b[j], acc[i][j], 0, 0, 0);
    asm volatile("s_waitcnt lgkmcnt(0)" ::: "memory");   // reads retired before next barrier
    __builtin_amdgcn_sched_barrier(0);
  }
#undef GSTAGE

#pragma unroll
  for (int i = 0; i < 4; i++) {
#pragma unroll
    for (int j2 = 0; j2 < 4; j2++) {
      int mm = m0 + wr * 64 + i * 16 + (l >> 4) * 4 + j2;
      int bidx = mm >> 11, s = mm & 2047;
#pragma unroll
      for (int nj = 0; nj < 4; nj++) {
        int e = n0 + wc * 64 + nj * 16 + (l & 15);
        float val = acc[i][nj][j2] + bias[e];
        int h = e >> 6, dk = e & 63;
        int bh = bidx * H_ + h;
        if (which == 0)      Qw[(bh * S_ + s) * DK_ + dk] = f2b(val * LOG2E_OVER8);
        else if (which == 1) Kw[(bh * S_ + s) * DK_ + dk] = f2b(val);
        else                 VTw[(bh * DK_ + dk) * S_ + s] = f2b(val);
      }
    }
  }
}

// ---------------- flash attention v10 (verbatim revert: 43.4 us proven) ----------
#define KVB   32
#define SHALF 1024
__launch_bounds__(256, 3)
__global__ void attn_kernel(const short* __restrict__ Qw, const short* __restrict__ Kw,
                            const short* __restrict__ VTw, short* __restrict__ ctx) {
  __shared__ short Ksh[2][2][KVB * DK_];   // [stream][buf][32 rows][64]
  __shared__ short Vsh[2][2][KVB * DK_];   // [stream][buf] pair-packed rows

  const int t = threadIdx.x, l = t & 63, w = t >> 6;
  const int s = w >> 1, qh = w & 1;
  const int L = blockIdx.y * 32 + blockIdx.x;
  const int xcd = L & 7, idx = L >> 3;
  const int bh = xcd * 3 + (idx >> 5);
  const int qblk = idx & 31;
  const int q0 = qblk * 64 + qh * 32;
  const int bq = bh / H_, h = bh - bq * H_;
  const short* Qh = Qw + bh * S_ * DK_;
  const short* Kh = Kw + (bh * S_ + s * SHALF) * DK_;
  const short* Vh = VTw + bh * DK_ * S_ + s * SHALF;

  const int tt = t & 127;
  const int kr0 = tt >> 3, kc0 = tt & 7;
  const int koff0 = kr0 * DK_ + ((kc0 ^ (kr0 & 7)) << 3);
  const int vc8 = (tt & 7) ^ ((tt >> 3) & 7);
  const int vr0 = 2 * (tt >> 3) + (vc8 >> 2);
  const int voff0 = vr0 * S_ + ((vc8 & 3) << 3);

#define STAGE(buf, kt) do { \
    gl_lds16(Kh + (kt) * DK_ + koff0,        &Ksh[s][buf][tt * 8]); \
    gl_lds16(Kh + (kt) * DK_ + koff0 + 1024, &Ksh[s][buf][tt * 8 + 1024]); \
    gl_lds16(Vh + (kt) + voff0,              &Vsh[s][buf][tt * 8]); \
    gl_lds16(Vh + (kt) + voff0 + 32 * S_,    &Vsh[s][buf][tt * 8 + 1024]); \
  } while (0)

  short8 qf[2][2];
#pragma unroll
  for (int mi = 0; mi < 2; mi++)
#pragma unroll
    for (int ks = 0; ks < 2; ks++)
      qf[mi][ks] = *(const short8*)&Qh[(q0 + 16 * mi + (l & 15)) * DK_ + ks * 32 + (l >> 4) * 8];

  f32x4 acc_o[2][4] = {};
  float l_run[2] = {0.f, 0.f};   // per-lane PARTIAL sums

  STAGE(0, 0);
  __syncthreads();
  int cur = 0;

  for (int kt = 0; kt < SHALF; kt += KVB) {
    if (kt + KVB < SHALF) STAGE(cur ^ 1, kt + KVB);

    f32x4 acc_s[2][2] = {};
    __builtin_amdgcn_s_setprio(1);
#pragma unroll
    for (int ni = 0; ni < 2; ni++) {
      int r = (l & 15) + 16 * ni;
#pragma unroll
      for (int ks = 0; ks < 2; ks++) {
        int cc = (l >> 4) + 4 * ks;
        short8 kf = *(const short8*)&Ksh[s][cur][r * DK_ + ((cc ^ (r & 7)) << 3)];
        acc_s[0][ni] = __builtin_amdgcn_mfma_f32_16x16x32_bf16(kf, qf[0][ks], acc_s[0][ni], 0, 0, 0);
        acc_s[1][ni] = __builtin_amdgcn_mfma_f32_16x16x32_bf16(kf, qf[1][ks], acc_s[1][ni], 0, 0, 0);
      }
    }
    __builtin_amdgcn_s_setprio(0);

#pragma unroll
    for (int mi = 0; mi < 2; mi++) {
      float sum = 0.f;
#pragma unroll
      for (int ni = 0; ni < 2; ni++)
#pragma unroll
        for (int j = 0; j < 4; j++) {
          float p = __builtin_amdgcn_exp2f(acc_s[mi][ni][j]);
          acc_s[mi][ni][j] = p;
          sum += p;
        }
      l_run[mi] += sum;
    }

    union PK { unsigned u[4]; short8 v; } pa0, pa1;
    pa0.u[0] = cvt_pk_bf16(acc_s[0][0][0], acc_s[0][0][1]);
    pa0.u[1] = cvt_pk_bf16(acc_s[0][0][2], acc_s[0][0][3]);
    pa0.u[2] = cvt_pk_bf16(acc_s[0][1][0], acc_s[0][1][1]);
    pa0.u[3] = cvt_pk_bf16(acc_s[0][1][2], acc_s[0][1][3]);
    pa1.u[0] = cvt_pk_bf16(acc_s[1][0][0], acc_s[1][0][1]);
    pa1.u[1] = cvt_pk_bf16(acc_s[1][0][2], acc_s[1][0][3]);
    pa1.u[2] = cvt_pk_bf16(acc_s[1][1][0], acc_s[1][1][1]);
    pa1.u[3] = cvt_pk_bf16(acc_s[1][1][2], acc_s[1][1][3]);

    __builtin_amdgcn_s_setprio(1);
    {
      const int cc = l >> 4;
      union V8 { short4 h[2]; short8 v; };
#pragma unroll
      for (int nd = 0; nd < 4; nd++) {
        int vr = (l & 15) + 16 * nd, rp = vr >> 1;
        int ph0 = (((vr & 1) << 2) | (cc >> 1)) ^ (rp & 7);
        int ph1 = (((vr & 1) << 2) | (2 + (cc >> 1))) ^ (rp & 7);
        V8 vf;
        vf.h[0] = *(const short4*)&Vsh[s][cur][rp * 64 + ph0 * 8 + (cc & 1) * 4];
        vf.h[1] = *(const short4*)&Vsh[s][cur][rp * 64 + ph1 * 8 + (cc & 1) * 4];
        acc_o[0][nd] = __builtin_amdgcn_mfma_f32_16x16x32_bf16(pa0.v, vf.v, acc_o[0][nd], 0, 0, 0);
        acc_o[1][nd] = __builtin_amdgcn_mfma_f32_16x16x32_bf16(pa1.v, vf.v, acc_o[1][nd], 0, 0, 0);
      }
    }
    __builtin_amdgcn_s_setprio(0);

    __syncthreads();
    cur ^= 1;
  }

#pragma unroll
  for (int mi = 0; mi < 2; mi++) {
    l_run[mi] += __shfl_xor(l_run[mi], 16);
    l_run[mi] += __shfl_xor(l_run[mi], 32);
  }

  __syncthreads();
  float* Oshf = (float*)&Ksh[0][0][0];
  float* Lsh  = (float*)&Vsh[0][0][0];
  if (s == 1) {
#pragma unroll
    for (int mi = 0; mi < 2; mi++)
#pragma unroll
      for (int nd = 0; nd < 4; nd++)
#pragma unroll
        for (int j = 0; j < 4; j++)
          Oshf[qh * 2048 + (16 * mi + (l >> 4) * 4 + j) * 64 + (l & 15) + 16 * nd] = acc_o[mi][nd][j];
    if (l < 16) {
      Lsh[(qh * 2 + 0) * 16 + l] = l_run[0];
      Lsh[(qh * 2 + 1) * 16 + l] = l_run[1];
    }
  }
  __syncthreads();
  if (s == 0) {
#pragma unroll
    for (int mi = 0; mi < 2; mi++) {
#pragma unroll
      for (int j = 0; j < 4; j++) {
        int src = ((l >> 4) << 2) + j;
        float llo = __shfl(l_run[mi], src);
        float lhi = Lsh[(qh * 2 + mi) * 16 + src];
        float inv = 1.f / (llo + lhi);
        int srow = q0 + 16 * mi + src;
#pragma unroll
        for (int nd = 0; nd < 4; nd++) {
          float ohi = Oshf[qh * 2048 + (16 * mi + src) * 64 + (l & 15) + 16 * nd];
          float val = (acc_o[mi][nd][j] + ohi) * inv;
          ctx[(bq * S_ + srow) * D_ + h * DK_ + (l & 15) + 16 * nd] = f2b(val);
        }
      }
    }
  }
#undef STAGE
}

// ------- output projection: 128x128, 3-buffer ring, counted vmcnt (T3/T4) -------
__launch_bounds__(256)
__global__ void oproj_kernel(const short* __restrict__ ctx, const short* __restrict__ Wo,
                             const float* __restrict__ bo, float* __restrict__ out) {
  __shared__ short As[3][128 * 32];
  __shared__ short Bs[3][128 * 32];
  const int n0 = blockIdx.x * 128, m0 = blockIdx.y * 128;
  const int t = threadIdx.x, l = t & 63, w = t >> 6;
  const int wr = w >> 1, wc = w & 1;

  f32x4 acc[4][4] = {};
  const int srow = t >> 2, sseg = (t & 3) * 8;

#define GSTAGE(buf, k0) do { \
    gl_lds16(ctx + (m0 + srow) * D_ + (k0) + sseg,      &As[buf][t * 8]); \
    gl_lds16(ctx + (m0 + 64 + srow) * D_ + (k0) + sseg, &As[buf][(t + 256) * 8]); \
    gl_lds16(Wo  + (n0 + srow) * D_ + (k0) + sseg,      &Bs[buf][t * 8]); \
    gl_lds16(Wo  + (n0 + 64 + srow) * D_ + (k0) + sseg, &Bs[buf][(t + 256) * 8]); \
  } while (0)

  GSTAGE(0, 0);
  GSTAGE(1, 32);
  int step = 0;
#pragma unroll 1
  for (int k0 = 0; k0 < D_; k0 += 32, step++) {
    if (k0 + 32 < D_) {
      asm volatile("s_waitcnt vmcnt(4)" ::: "memory");
    } else {
      asm volatile("s_waitcnt vmcnt(0)" ::: "memory");
    }
    __builtin_amdgcn_sched_barrier(0);
    __builtin_amdgcn_s_barrier();
    if (k0 + 64 < D_) GSTAGE((step + 2) % 3, k0 + 64);
    const int cb = step % 3;
    short8 a[4], b[4];
#pragma unroll
    for (int i = 0; i < 4; i++)
      a[i] = *(const short8*)&As[cb][(wr * 64 + i * 16 + (l & 15)) * 32 + (l >> 4) * 8];
#pragma unroll
    for (int i = 0; i < 4; i++)
      b[i] = *(const short8*)&Bs[cb][(wc * 64 + i * 16 + (l & 15)) * 32 + (l >> 4) * 8];
#pragma unroll
    for (int i = 0; i < 4; i++)
#pragma unroll
      for (int j = 0; j < 4; j++)
        acc[i][j] = __builtin_amdgcn_mfma_f32_16x16x32_bf16(a[i], b[j], acc[i][j], 0, 0, 0);
    asm volatile("s_waitcnt lgkmcnt(0)" ::: "memory");
    __builtin_amdgcn_sched_barrier(0);
  }
#undef GSTAGE

#pragma unroll
  for (int i = 0; i < 4; i++) {
#pragma unroll
    for (int j2 = 0; j2 < 4; j2++) {
      int mm = m0 + wr * 64 + i * 16 + (l >> 4) * 4 + j2;
#pragma unroll
      for (int nj = 0; nj < 4; nj++) {
        int e = n0 + wc * 64 + nj * 16 + (l & 15);
        out[mm * D_ + e] = acc[i][nj][j2] + bo[e];
      }
    }
  }
}

extern "C" void kernel_launch(void* const* d_in, const int* in_sizes, int n_in,
                              void* d_out, int out_size, void* d_ws, size_t ws_size,
                              hipStream_t stream) {
  (void)in_sizes; (void)n_in; (void)out_size; (void)ws_size;
  const float* x  = (const float*)d_in[0];
  const float* wq = (const float*)d_in[1];
  const float* bq = (const float*)d_in[2];
  const float* wk = (const float*)d_in[3];
  const float* bk = (const float*)d_in[4];
  const float* wv = (const float*)d_in[5];
  const float* bv = (const float*)d_in[6];
  const float* wo = (const float*)d_in[7];
  const float* bo = (const float*)d_in[8];
  float* out = (float*)d_out;

  short* xb  = (short*)d_ws;            // R*D bf16
  short* wb  = xb + R_ * D_;            // 4*D*D bf16 (q,k,v,o)
  short* Qw  = wb + 4 * D_ * D_;        // [B,H,S,DK]
  short* Kw  = Qw + R_ * D_;            // [B,H,S,DK]
  short* VTw = Kw + R_ * D_;            // [B,H,DK,S]
  short* ctx = VTw + R_ * D_;           // [B,S,D]

  cvt_kernel<<<5376, 256, 0, stream>>>(x, wq, wk, wv, wo, xb, wb);
  qkv_gemm_kernel<<<dim3(6, 32, 3), 256, 0, stream>>>(xb, wb, bq, bk, bv, Qw, Kw, VTw);
  attn_kernel<<<dim3(32, 24), 256, 0, stream>>>(Qw, Kw, VTw, ctx);
  oproj_kernel<<<dim3(6, 32), 256, 0, stream>>>(ctx, wb + 3 * D_ * D_, bo, out);
}